// Round 14
// baseline (257.925 us; speedup 1.0000x reference)
//
#include <hip/hip_runtime.h>
#include <math.h>

// ---------------------------------------------------------------------------
// Mamba2-style 2D SSM block. bf16 intermediates + MFMA for inproj/KV/y5/conv3.
// B=8, D_MODEL=256, L=64*64=4096, D_IN_PROJ=1160, D_SSM=512, NH=8, HD=64,
// D_STATE=64, CONV_DIM=640, COUT=256.
// ---------------------------------------------------------------------------

constexpr int BATCH  = 8;
constexpr int CIN    = 256;
constexpr int HH     = 64, WW = 64;
constexpr int L      = HH * WW;      // 4096
constexpr int DPROJ  = 1160;
constexpr int DSSM   = 512;
constexpr int DSTATE = 64;
constexpr int NH     = 8;
constexpr int HD     = 64;
constexpr int CONVD  = 640;
constexpr int COUT   = 256;
constexpr float EPS  = 1e-5f;

typedef __attribute__((ext_vector_type(8))) short short8;   // 8 bf16 (4 VGPR)
typedef __attribute__((ext_vector_type(4))) float f32x4;

static __device__ __forceinline__ float silu_f(float x) {
    return x / (1.f + __expf(-x));
}
static __device__ __forceinline__ float bf2f(unsigned short u) {
    return __uint_as_float(((unsigned)u) << 16);
}
static __device__ __forceinline__ unsigned short f2bf(float f) {
    unsigned x = __float_as_uint(f);
    unsigned r = (x + 0x7FFFu + ((x >> 16) & 1u)) >> 16;   // RNE
    return (unsigned short)r;
}

// async global->LDS, 16B per lane (dest must be wave-uniform base + lane*16)
static __device__ __forceinline__ void gl2lds16(const unsigned short* g, short* l) {
    __builtin_amdgcn_global_load_lds(
        (const __attribute__((address_space(1))) unsigned int*)g,
        (__attribute__((address_space(3))) unsigned int*)l, 16, 0, 0);
}

// ---------------------------------------------------------------------------
// K0a: in_proj weights -> bf16 K-tiles with XOR-swizzled slots.
// Wt2[oblk][ks][row][slot'][8] ; slot' = slot ^ (row&3); o>=DPROJ zero-padded.
// ---------------------------------------------------------------------------
__global__ __launch_bounds__(256) void k_wb2(const float* __restrict__ W,
                                             unsigned short* __restrict__ Wt2) {
    int idx8 = blockIdx.x * 256 + threadIdx.x;   // 0..40959, 8 elements each
    int tile = idx8 >> 9;                        // 0..79 = oblk*8 + ks
    int within = (idx8 & 511) * 8;               // element offset in 4096-tile
    int row = within >> 5;
    int slp = (within >> 3) & 3;                 // stored (swizzled) slot
    int oblk = tile >> 3, ks = tile & 7;
    int o = oblk * 128 + row;
    int c = ks * 32 + (slp ^ (row & 3)) * 8;     // source slot
    unsigned short s[8] = {0, 0, 0, 0, 0, 0, 0, 0};
    if (o < DPROJ) {
        float4 v0 = *(const float4*)(W + (size_t)o * CIN + c);
        float4 v1 = *(const float4*)(W + (size_t)o * CIN + c + 4);
        s[0] = f2bf(v0.x); s[1] = f2bf(v0.y); s[2] = f2bf(v0.z); s[3] = f2bf(v0.w);
        s[4] = f2bf(v1.x); s[5] = f2bf(v1.y); s[6] = f2bf(v1.z); s[7] = f2bf(v1.w);
    }
    *(uint4*)(Wt2 + (size_t)tile * 4096 + within) = *(uint4*)s;
}

// ---------------------------------------------------------------------------
// K0b: u (f32, [b][c][l]) -> uTt bf16 K-tiles (same layout/swizzle as Wt2):
// uTt[b][lblk][ks][row][slot'][8], lblk = l/128, row = l%128.
// ---------------------------------------------------------------------------
__global__ __launch_bounds__(256) void k_uT(const float* __restrict__ u,
                                            unsigned short* __restrict__ uTt) {
    __shared__ float Ts[32][33];
    int l0 = blockIdx.x * 32;
    int c0 = blockIdx.y * 32;          // multiple of 32 -> ks = c0/32
    int b  = blockIdx.z;
    int tid = threadIdx.x;
    {
        int r = tid >> 3, c4 = tid & 7;     // row = c-index, 4 l's
        float4 v = *(const float4*)(u + ((size_t)b * CIN + c0 + r) * L + l0 + c4 * 4);
        Ts[r][c4 * 4 + 0] = v.x;
        Ts[r][c4 * 4 + 1] = v.y;
        Ts[r][c4 * 4 + 2] = v.z;
        Ts[r][c4 * 4 + 3] = v.w;
    }
    __syncthreads();
    {
        int lr = tid >> 3, cg = tid & 7;    // lr: l within 32; cg: 4-c group
        unsigned short s[4];
#pragma unroll
        for (int j = 0; j < 4; ++j) s[j] = f2bf(Ts[cg * 4 + j][lr]);
        int lg = l0 + lr;
        int tile = ((b * 32 + (lg >> 7)) << 3) + (c0 >> 5);
        int row = lg & 127;
        int slot = (cg >> 1) ^ (row & 3);
        size_t off = (size_t)tile * 4096 + row * 32 + slot * 8 + (cg & 1) * 4;
        *(uint2*)(uTt + off) = *(uint2*)s;
    }
}

// ---------------------------------------------------------------------------
// K0c: conv3 weight prep: Wb2[tap][ci>>3][co][ci&7] = bf16(Wt[co][ci][tap])
// ---------------------------------------------------------------------------
__global__ __launch_bounds__(256) void k_wprep(const float* __restrict__ Wt,
                                               unsigned short* __restrict__ Wb2) {
    int i = blockIdx.x * 256 + threadIdx.x;    // co*512 + ci
    int co = i >> 9, ci = i & 511;
    const float* src = Wt + (size_t)i * 9;
#pragma unroll
    for (int tap = 0; tap < 9; ++tap) {
        Wb2[(((size_t)tap * 64 + (ci >> 3)) * 256 + co) * 8 + (ci & 7)] = f2bf(src[tap]);
    }
}

// ---------------------------------------------------------------------------
// K1: in-projection via MFMA, m97-style: global_load_lds staging, double
// buffer, swizzled ds_read_b128, one barrier per K-step. 128l x 128o block.
// ---------------------------------------------------------------------------
__global__ __launch_bounds__(256) void k_inprojm(const unsigned short* __restrict__ Wt2,
                                                 const unsigned short* __restrict__ uTt,
                                                 unsigned short* __restrict__ zx) {
    __shared__ short Ab[2][4096];      // 8 KB each
    __shared__ short Bbuf[2][4096];
    int lblk = blockIdx.x, oblk = blockIdx.y, b = blockIdx.z;
    int tid = threadIdx.x, lane = tid & 63, w = tid >> 6;
    int laneN = lane & 15, laneK = lane >> 4;

    const unsigned short* At = uTt + (size_t)(b * 32 + lblk) * 8 * 4096;
    const unsigned short* Bt = Wt2 + (size_t)oblk * 8 * 4096;

    f32x4 acc[4][4];
#pragma unroll
    for (int mt = 0; mt < 4; ++mt)
#pragma unroll
        for (int nt = 0; nt < 4; ++nt) acc[mt][nt] = (f32x4){0.f, 0.f, 0.f, 0.f};

    gl2lds16(At + tid * 8,        &Ab[0][tid * 8]);
    gl2lds16(At + 2048 + tid * 8, &Ab[0][2048 + tid * 8]);
    gl2lds16(Bt + tid * 8,        &Bbuf[0][tid * 8]);
    gl2lds16(Bt + 2048 + tid * 8, &Bbuf[0][2048 + tid * 8]);
    __syncthreads();

    int arow = (w & 1) * 64;
    int brow = (w >> 1) * 64;
    int asl = (laneK ^ (laneN & 3)) * 8;

    int cur = 0;
    for (int ks = 0; ks < 8; ++ks) {
        if (ks < 7) {
            const unsigned short* an = At + (size_t)(ks + 1) * 4096;
            const unsigned short* bn = Bt + (size_t)(ks + 1) * 4096;
            int c2 = cur ^ 1;
            gl2lds16(an + tid * 8,        &Ab[c2][tid * 8]);
            gl2lds16(an + 2048 + tid * 8, &Ab[c2][2048 + tid * 8]);
            gl2lds16(bn + tid * 8,        &Bbuf[c2][tid * 8]);
            gl2lds16(bn + 2048 + tid * 8, &Bbuf[c2][2048 + tid * 8]);
        }
        short8 av[4], bv[4];
#pragma unroll
        for (int mt = 0; mt < 4; ++mt)
            av[mt] = *(const short8*)&Ab[cur][(arow + mt * 16 + laneN) * 32 + asl];
#pragma unroll
        for (int nt = 0; nt < 4; ++nt)
            bv[nt] = *(const short8*)&Bbuf[cur][(brow + nt * 16 + laneN) * 32 + asl];
#pragma unroll
        for (int mt = 0; mt < 4; ++mt)
#pragma unroll
            for (int nt = 0; nt < 4; ++nt)
                acc[mt][nt] = __builtin_amdgcn_mfma_f32_16x16x32_bf16(av[mt], bv[nt], acc[mt][nt], 0, 0, 0);
        __syncthreads();
        cur ^= 1;
    }

    unsigned short* zb = zx + (size_t)b * DPROJ * L;
    int lbase = lblk * 128 + arow;
#pragma unroll
    for (int nt = 0; nt < 4; ++nt) {
        int o = oblk * 128 + brow + nt * 16 + laneN;
        if (o < DPROJ) {
#pragma unroll
            for (int mt = 0; mt < 4; ++mt) {
                unsigned short s[4] = {f2bf(acc[mt][nt].x), f2bf(acc[mt][nt].y),
                                       f2bf(acc[mt][nt].z), f2bf(acc[mt][nt].w)};
                *(uint2*)(zb + (size_t)o * L + lbase + mt * 16 + laneK * 4) = *(uint2*)s;
            }
        }
    }
}

// ---------------------------------------------------------------------------
// K2: dt causal conv (K=4) + SiLU, fold in A
// ---------------------------------------------------------------------------
__global__ __launch_bounds__(256) void k_dtdA(const unsigned short* __restrict__ zx,
                                              const float* __restrict__ cw,
                                              const float* __restrict__ cb,
                                              const float* __restrict__ Alog,
                                              float* __restrict__ dA) {
    int idx = blockIdx.x * 256 + threadIdx.x;
    int l = idx & (L - 1);
    int h = (idx >> 12) & (NH - 1);
    int b = idx >> 15;
    const unsigned short* row = zx + ((size_t)b * DPROJ + DSSM + CONVD + h) * L;
    float y = cb[h];
#pragma unroll
    for (int k = 0; k < 4; ++k) {
        int ls = l + k - 3;
        if (ls >= 0) y += cw[h * 4 + k] * bf2f(row[ls]);
    }
    dA[idx] = silu_f(y) * (-__expf(Alog[h]));
}

// ---------------------------------------------------------------------------
// K3: xBC causal conv (K=3) + SiLU, vectorized by 8 along l.
// ---------------------------------------------------------------------------
__global__ __launch_bounds__(256) void k_xbc(const unsigned short* __restrict__ zx,
                                             const float* __restrict__ cw,
                                             const float* __restrict__ cb,
                                             unsigned short* __restrict__ xbc) {
    int idx = blockIdx.x * 256 + threadIdx.x;
    int lg = idx & (L / 8 - 1);
    int c  = (idx >> 9) % CONVD;
    int b  = idx / (CONVD * (L / 8));
    int l0 = lg * 8;
    const unsigned short* row = zx + ((size_t)b * DPROJ + DSSM + c) * L;
    float x[10];
    uint4 raw = *(const uint4*)(row + l0);
    const unsigned short* s = (const unsigned short*)&raw;
#pragma unroll
    for (int t = 0; t < 8; ++t) x[2 + t] = bf2f(s[t]);
    if (l0 > 0) { x[0] = bf2f(row[l0 - 2]); x[1] = bf2f(row[l0 - 1]); }
    else        { x[0] = 0.f; x[1] = 0.f; }
    float w0 = cw[c * 3 + 0], w1 = cw[c * 3 + 1], w2 = cw[c * 3 + 2], bb = cb[c];
    uint4 o;
    unsigned short* os = (unsigned short*)&o;
#pragma unroll
    for (int t = 0; t < 8; ++t) {
        float y = bb + w0 * x[t] + w1 * x[t + 1] + w2 * x[t + 2];
        os[t] = f2bf(silu_f(y));
    }
    *(uint4*)(xbc + ((size_t)b * CONVD + c) * L + l0) = o;
}

// ---------------------------------------------------------------------------
// K3b: CT[b][l][n] = xbc[b][DSSM+DSTATE+n][l]  (bf16 32x32 tile transpose)
// ---------------------------------------------------------------------------
__global__ __launch_bounds__(256) void k_ct(const unsigned short* __restrict__ xbc,
                                            unsigned short* __restrict__ CT) {
    __shared__ short Ts[32][33];
    int l0 = blockIdx.x * 32;
    int n0 = blockIdx.y * 32;
    int b  = blockIdx.z;
    int tid = threadIdx.x;
    {
        int r = tid >> 3, q = tid & 7;      // row = n-index, 4 l's
        uint2 v = *(const uint2*)(xbc + ((size_t)b * CONVD + DSSM + DSTATE + n0 + r) * L + l0 + q * 4);
        const unsigned short* s = (const unsigned short*)&v;
#pragma unroll
        for (int t = 0; t < 4; ++t) Ts[r][q * 4 + t] = (short)s[t];
    }
    __syncthreads();
    {
        int lr = tid >> 3, qn = tid & 7;    // row = l-index, 4 n's
        unsigned short s[4];
#pragma unroll
        for (int t = 0; t < 4; ++t) s[t] = (unsigned short)Ts[qn * 4 + t][lr];
        *(uint2*)(CT + ((size_t)b * L + l0 + lr) * DSTATE + n0 + qn * 4) = *(uint2*)s;
    }
}

// ---------------------------------------------------------------------------
// K4: KV via MFMA. Per (b,h): KV[n][d] = sum_l (B[l][n]*dA[l]) * V[l][d].
// ---------------------------------------------------------------------------
__global__ __launch_bounds__(256) void k_kvm(const unsigned short* __restrict__ xbc,
                                             const float* __restrict__ dA,
                                             float* __restrict__ pKV) {
    __shared__ float red[4][4096];             // 64 KB
    int kc = blockIdx.x, h = blockIdx.y, b = blockIdx.z;
    int tid = threadIdx.x, lane = tid & 63, w = tid >> 6;
    int laneN = lane & 15, laneK = lane >> 4;

    const unsigned short* Bb = xbc + ((size_t)b * CONVD + DSSM) * L;
    const unsigned short* Vb = xbc + ((size_t)b * CONVD + h * HD) * L;
    const float* dAp = dA + ((size_t)b * NH + h) * L;

    f32x4 acc[4][4];
#pragma unroll
    for (int mt = 0; mt < 4; ++mt)
#pragma unroll
        for (int nt = 0; nt < 4; ++nt) acc[mt][nt] = (f32x4){0.f, 0.f, 0.f, 0.f};

    int kbase = kc * 512 + w * 128;
#pragma unroll
    for (int ks = 0; ks < 4; ++ks) {
        int kl = kbase + ks * 32 + laneK * 8;
        float4 da0 = *(const float4*)(dAp + kl);
        float4 da1 = *(const float4*)(dAp + kl + 4);
        float dav[8] = {da0.x, da0.y, da0.z, da0.w, da1.x, da1.y, da1.z, da1.w};
        short8 afr[4];
#pragma unroll
        for (int mt = 0; mt < 4; ++mt) {
            uint4 raw = *(const uint4*)(Bb + (size_t)(mt * 16 + laneN) * L + kl);
            const unsigned short* s = (const unsigned short*)&raw;
            short8 af;
#pragma unroll
            for (int j = 0; j < 8; ++j) af[j] = (short)f2bf(bf2f(s[j]) * dav[j]);
            afr[mt] = af;
        }
#pragma unroll
        for (int nt = 0; nt < 4; ++nt) {
            short8 bfr = *(const short8*)(Vb + (size_t)(nt * 16 + laneN) * L + kl);
#pragma unroll
            for (int mt = 0; mt < 4; ++mt)
                acc[mt][nt] = __builtin_amdgcn_mfma_f32_16x16x32_bf16(afr[mt], bfr, acc[mt][nt], 0, 0, 0);
        }
    }

#pragma unroll
    for (int mt = 0; mt < 4; ++mt)
#pragma unroll
        for (int nt = 0; nt < 4; ++nt)
#pragma unroll
            for (int j = 0; j < 4; ++j)
                red[w][(mt * 16 + laneK * 4 + j) * 64 + nt * 16 + laneN] = acc[mt][nt][j];
    __syncthreads();

    float* dst = pKV + (((size_t)(b * NH + h) * 8 + kc) * 4096);
#pragma unroll
    for (int q = 0; q < 4; ++q) {
        int off = q * 1024 + tid * 4;
        float4 s0 = *(const float4*)&red[0][off];
        float4 s1 = *(const float4*)&red[1][off];
        float4 s2 = *(const float4*)&red[2][off];
        float4 s3 = *(const float4*)&red[3][off];
        float4 r;
        r.x = s0.x + s1.x + s2.x + s3.x;
        r.y = s0.y + s1.y + s2.y + s3.y;
        r.z = s0.z + s1.z + s2.z + s3.z;
        r.w = s0.w + s1.w + s2.w + s3.w;
        *(float4*)(dst + off) = r;
    }
}

// ---------------------------------------------------------------------------
// K4b (fused): reduce 8 k-chunk partials AND write transposed bf16 KVt[bh][d][n].
// One block per bh.
// ---------------------------------------------------------------------------
__global__ __launch_bounds__(256) void k_kvrt(const float* __restrict__ pKV,
                                              unsigned short* __restrict__ KVt) {
    __shared__ float Ts[64][65];
    int bh = blockIdx.x;
    int tid = threadIdx.x;
    const float* src = pKV + (size_t)bh * 8 * 4096;
#pragma unroll
    for (int j = 0; j < 16; ++j) {
        int idx = j * 256 + tid;           // [n][d] flat
        float s = 0.f;
#pragma unroll
        for (int kc = 0; kc < 8; ++kc) s += src[(size_t)kc * 4096 + idx];
        Ts[idx >> 6][idx & 63] = s;
    }
    __syncthreads();
    unsigned short* dst = KVt + (size_t)bh * 4096;
#pragma unroll
    for (int j = 0; j < 4; ++j) {
        int idx = j * 256 + tid;           // 0..1023
        int d = idx >> 4, q = idx & 15;
        unsigned short s[4];
#pragma unroll
        for (int t = 0; t < 4; ++t) s[t] = f2bf(Ts[q * 4 + t][d]);
        *(uint2*)(dst + d * 64 + q * 4) = *(uint2*)s;
    }
}

// ---------------------------------------------------------------------------
// K5 (fused): y = C·KV (MFMA) + V*D, gate silu(silu(conv_z)), RMSNorm over
// all 512 channels, write ynT[b][l][c] directly. Block = (32 l, b); 4 waves,
// each 32l x 128d (2 heads): acc[2][8]. Softmax-free single-pass norm:
// pass1 computes yg in-register (overwrites acc) + per-l sum(yg^2) via
// shfl_xor over laneN + LDS cross-wave reduce; pass2 scales & stores.
// ---------------------------------------------------------------------------
__global__ __launch_bounds__(256) void k_y5n(const unsigned short* __restrict__ CT,
                                             const unsigned short* __restrict__ KVt,
                                             const unsigned short* __restrict__ xbc,
                                             const unsigned short* __restrict__ zx,
                                             const float* __restrict__ zw,
                                             const float* __restrict__ zb,
                                             const float* __restrict__ Dp,
                                             const float* __restrict__ nw,
                                             unsigned short* __restrict__ ynT) {
    __shared__ float red[32][4];
    int l0 = blockIdx.x * 32;
    int b  = blockIdx.y;
    int tid = threadIdx.x, lane = tid & 63, w = tid >> 6;
    int laneN = lane & 15, laneK = lane >> 4;

    const unsigned short* ctb = CT + (size_t)b * L * DSTATE;
    const unsigned short* xb  = xbc + (size_t)b * CONVD * L;

    f32x4 acc[2][8];
#pragma unroll
    for (int mt = 0; mt < 2; ++mt)
#pragma unroll
        for (int nt = 0; nt < 8; ++nt) acc[mt][nt] = (f32x4){0.f, 0.f, 0.f, 0.f};

#pragma unroll
    for (int ks = 0; ks < 2; ++ks) {
        int ko = ks * 32 + laneK * 8;
        short8 av[2];
#pragma unroll
        for (int mt = 0; mt < 2; ++mt)
            av[mt] = *(const short8*)(ctb + (size_t)(l0 + mt * 16 + laneN) * DSTATE + ko);
#pragma unroll
        for (int nt = 0; nt < 8; ++nt) {
            int head = w * 2 + (nt >> 2);
            const unsigned short* kvb = KVt + (size_t)(b * NH + head) * (HD * DSTATE);
            short8 bv = *(const short8*)(kvb + (size_t)((nt & 3) * 16 + laneN) * DSTATE + ko);
            acc[0][nt] = __builtin_amdgcn_mfma_f32_16x16x32_bf16(av[0], bv, acc[0][nt], 0, 0, 0);
            acc[1][nt] = __builtin_amdgcn_mfma_f32_16x16x32_bf16(av[1], bv, acc[1][nt], 0, 0, 0);
        }
    }

    // pass1: +V*D, gate, square-sum; acc := yg
    float ps[2][4];
#pragma unroll
    for (int mt = 0; mt < 2; ++mt)
#pragma unroll
        for (int j = 0; j < 4; ++j) ps[mt][j] = 0.f;

#pragma unroll
    for (int nt = 0; nt < 8; ++nt) {
        int head = w * 2 + (nt >> 2);
        int c = head * 64 + (nt & 3) * 16 + laneN;
        float Dh = Dp[head];
        float w0 = zw[c * 3 + 0], w1 = zw[c * 3 + 1], w2 = zw[c * 3 + 2];
        float bz = zb[c];
        const unsigned short* vrow = xb + (size_t)c * L;
        const unsigned short* zrow = zx + ((size_t)b * DPROJ + c) * L;
#pragma unroll
        for (int mt = 0; mt < 2; ++mt) {
            int lpos = l0 + mt * 16 + laneK * 4;
            float v[4];
            {
                uint2 raw = *(const uint2*)(vrow + lpos);
                const unsigned short* s = (const unsigned short*)&raw;
#pragma unroll
                for (int t = 0; t < 4; ++t) v[t] = bf2f(s[t]);
            }
            float zv[8];
            if (lpos >= 4) {
                uint2 z0 = *(const uint2*)(zrow + lpos - 4);
                const unsigned short* s = (const unsigned short*)&z0;
#pragma unroll
                for (int t = 0; t < 4; ++t) zv[t] = bf2f(s[t]);
            } else {
                zv[0] = zv[1] = zv[2] = zv[3] = 0.f;
            }
            {
                uint2 z1 = *(const uint2*)(zrow + lpos);
                const unsigned short* s = (const unsigned short*)&z1;
#pragma unroll
                for (int t = 0; t < 4; ++t) zv[4 + t] = bf2f(s[t]);
            }
#pragma unroll
            for (int j = 0; j < 4; ++j) {
                float y = acc[mt][nt][j] + v[j] * Dh;
                float zy = bz + w0 * zv[j + 2] + w1 * zv[j + 3] + w2 * zv[j + 4];
                float yg = y * silu_f(silu_f(zy));
                ps[mt][j] += yg * yg;
                acc[mt][nt][j] = yg;
            }
        }
    }

    // reduce ps over laneN (masks 1,2,4,8 stay within laneN bits)
#pragma unroll
    for (int m = 1; m <= 8; m <<= 1) {
#pragma unroll
        for (int mt = 0; mt < 2; ++mt)
#pragma unroll
            for (int j = 0; j < 4; ++j)
                ps[mt][j] += __shfl_xor(ps[mt][j], m, 64);
    }
    if (laneN == 0) {
#pragma unroll
        for (int mt = 0; mt < 2; ++mt)
#pragma unroll
            for (int j = 0; j < 4; ++j)
                red[mt * 16 + laneK * 4 + j][w] = ps[mt][j];
    }
    __syncthreads();

    float rr[2][4];
#pragma unroll
    for (int mt = 0; mt < 2; ++mt)
#pragma unroll
        for (int j = 0; j < 4; ++j) {
            int ll = mt * 16 + laneK * 4 + j;
            float s = red[ll][0] + red[ll][1] + red[ll][2] + red[ll][3];
            rr[mt][j] = rsqrtf(s * (1.f / DSSM) + EPS);
        }

    // pass2: scale + store ynT[b][l][c]
#pragma unroll
    for (int nt = 0; nt < 8; ++nt) {
        int c = (w * 2 + (nt >> 2)) * 64 + (nt & 3) * 16 + laneN;
        float nwc = nw[c];
#pragma unroll
        for (int mt = 0; mt < 2; ++mt) {
            int lpos = l0 + mt * 16 + laneK * 4;
            unsigned short* dst = ynT + ((size_t)b * L + lpos) * DSSM + c;
#pragma unroll
            for (int j = 0; j < 4; ++j)
                dst[(size_t)j * DSSM] = f2bf(acc[mt][nt][j] * rr[mt][j] * nwc);
        }
    }
}

// ---------------------------------------------------------------------------
// K6: 3x3 conv2d SAME via bf16 MFMA implicit GEMM (round-12 structure).
// ---------------------------------------------------------------------------
__global__ __launch_bounds__(256, 4) void k_conv3m(const unsigned short* __restrict__ ynT,
                                                   const unsigned short* __restrict__ Wb2,
                                                   float* __restrict__ out) {
    __shared__ short Alds[4 * 66 * 72];        // 38016 B
    int h0  = blockIdx.x * 2;
    int co0 = blockIdx.y * 64;
    int b   = blockIdx.z;
    int tid  = threadIdx.x;
    int lane = tid & 63;
    int wid  = tid >> 6;
    int wm = wid >> 1, wn = wid & 1;
    int laneN = lane & 15, laneK = lane >> 4;

    f32x4 acc[4][2];
#pragma unroll
    for (int mt = 0; mt < 4; ++mt)
#pragma unroll
        for (int nt = 0; nt < 2; ++nt) acc[mt][nt] = (f32x4){0.f, 0.f, 0.f, 0.f};

    const unsigned short* ynb = ynT + (size_t)b * L * DSSM;

    const int a_wi1 = tid >> 2, a_sl = tid & 3;

    if (tid < 64) {
        int rw = tid >> 3, q = tid & 7;
        int r = rw >> 1, wi = (rw & 1) ? 65 : 0;
        *(uint4*)&Alds[(r * 66 + wi) * 72 + q * 8] = make_uint4(0u, 0u, 0u, 0u);
    }

    uint4 pA[8];
#pragma unroll
    for (int j = 0; j < 4; ++j) {
        int hrow = h0 - 1 + j;
        bool ok = (hrow >= 0 && hrow < HH);
        const unsigned short* src = ynb + (size_t)(hrow * WW + a_wi1) * DSSM;
#pragma unroll
        for (int s2 = 0; s2 < 2; ++s2) {
            pA[j * 2 + s2] = make_uint4(0u, 0u, 0u, 0u);
            if (ok) pA[j * 2 + s2] = *(const uint4*)(src + (a_sl + s2 * 4) * 8);
        }
    }

    const unsigned short* wbp =
        Wb2 + ((size_t)laneK * 256 + co0 + wn * 32 + laneN) * 8;

    for (int ci0 = 0; ci0 < DSSM; ci0 += 64) {
        __syncthreads();
#pragma unroll
        for (int j = 0; j < 4; ++j)
#pragma unroll
            for (int s2 = 0; s2 < 2; ++s2)
                *(uint4*)&Alds[(j * 66 + a_wi1 + 1) * 72 + (a_sl + s2 * 4) * 8] = pA[j * 2 + s2];
        __syncthreads();

        if (ci0 + 64 < DSSM) {
            int cin = ci0 + 64;
#pragma unroll
            for (int j = 0; j < 4; ++j) {
                int hrow = h0 - 1 + j;
                bool ok = (hrow >= 0 && hrow < HH);
                const unsigned short* src = ynb + (size_t)(hrow * WW + a_wi1) * DSSM + cin;
#pragma unroll
                for (int s2 = 0; s2 < 2; ++s2) {
                    pA[j * 2 + s2] = make_uint4(0u, 0u, 0u, 0u);
                    if (ok) pA[j * 2 + s2] = *(const uint4*)(src + (a_sl + s2 * 4) * 8);
                }
            }
        }

        const unsigned short* wbc = wbp + (size_t)(ci0 >> 3) * 2048;
        short8 bC[4];   // [ks][nt]
#pragma unroll
        for (int ks = 0; ks < 2; ++ks)
#pragma unroll
            for (int nt = 0; nt < 2; ++nt)
                bC[ks * 2 + nt] = *(const short8*)(wbc + (size_t)ks * 8192 + nt * 128);
#pragma unroll
        for (int tap = 0; tap < 9; ++tap) {
            short8 bN[4];
#pragma unroll
            for (int q = 0; q < 4; ++q) bN[q] = bC[q];
            if (tap < 8) {
#pragma unroll
                for (int ks = 0; ks < 2; ++ks)
#pragma unroll
                    for (int nt = 0; nt < 2; ++nt)
                        bN[ks * 2 + nt] = *(const short8*)(wbc + (size_t)(tap + 1) * 131072 +
                                                          (size_t)ks * 8192 + nt * 128);
            }
            const int kh = tap / 3, kw = tap % 3;
#pragma unroll
            for (int ks = 0; ks < 2; ++ks) {
#pragma unroll
                for (int mt = 0; mt < 4; ++mt) {
                    short8 af = *(const short8*)&Alds[((wm + kh) * 66 + laneN + mt * 16 + kw) * 72 +
                                                      (laneK + ks * 4) * 8];
                    acc[mt][0] = __builtin_amdgcn_mfma_f32_16x16x32_bf16(af, bC[ks * 2 + 0], acc[mt][0], 0, 0, 0);
                    acc[mt][1] = __builtin_amdgcn_mfma_f32_16x16x32_bf16(af, bC[ks * 2 + 1], acc[mt][1], 0, 0, 0);
                }
            }
#pragma unroll
            for (int q = 0; q < 4; ++q) bC[q] = bN[q];
        }
    }

    float* ob = out + (size_t)b * COUT * L + (size_t)(h0 + wm) * WW;
#pragma unroll
    for (int mt = 0; mt < 4; ++mt) {
#pragma unroll
        for (int nt = 0; nt < 2; ++nt) {
            int co = co0 + wn * 32 + nt * 16 + laneN;
            float4 v = make_float4(acc[mt][nt].x, acc[mt][nt].y, acc[mt][nt].z, acc[mt][nt].w);
            *(float4*)(ob + (size_t)co * L + mt * 16 + laneK * 4) = v;
        }
    }
}

// ---------------------------------------------------------------------------
extern "C" void kernel_launch(void* const* d_in, const int* in_sizes, int n_in,
                              void* d_out, int out_size, void* d_ws, size_t ws_size,
                              hipStream_t stream) {
    const float* u          = (const float*)d_in[0];
    const float* in_proj_w  = (const float*)d_in[1];
    const float* conv_dt_w  = (const float*)d_in[2];
    const float* dt_bias    = (const float*)d_in[3];
    const float* conv_xBC_w = (const float*)d_in[4];
    const float* conv_xBC_b = (const float*)d_in[5];
    const float* conv_z_w   = (const float*)d_in[6];
    const float* conv_z_b   = (const float*)d_in[7];
    const float* A_log      = (const float*)d_in[8];
    const float* D_param    = (const float*)d_in[9];
    const float* norm_w     = (const float*)d_in[10];
    const float* out_w      = (const float*)d_in[11];
    float* out = (float*)d_out;

    // ws: zx | xbc | ynT (bf16) | dA | pKV (f32) | Wb2 | CT | KVt (bf16)
    const size_t n_zx  = (size_t)BATCH * DPROJ * L;
    const size_t n_xbc = (size_t)BATCH * CONVD * L;
    const size_t n_yn  = (size_t)BATCH * DSSM * L;
    const size_t n_dA  = (size_t)BATCH * NH * L;
    const size_t n_pKV = (size_t)BATCH * NH * 8 * DSTATE * HD;   // 2097152
    const size_t n_Wb2 = (size_t)9 * 64 * 256 * 8;
    const size_t n_ct  = (size_t)BATCH * L * DSTATE;             // 2097152
    const size_t n_kvt = (size_t)BATCH * NH * HD * DSTATE;       // 262144
    const size_t need  = 2 * (n_zx + n_xbc + n_yn + n_Wb2 + n_ct + n_kvt)
                       + 4 * (n_dA + n_pKV);
    if (ws_size < need) return;

    unsigned short* zx  = (unsigned short*)d_ws;
    unsigned short* xbc = zx + n_zx;
    unsigned short* ynT = xbc + n_xbc;
    float*          dAb = (float*)(ynT + n_yn);
    float*          pKV = dAb + n_dA;
    unsigned short* Wb2 = (unsigned short*)(pKV + n_pKV);
    unsigned short* CT  = Wb2 + n_Wb2;
    unsigned short* KVt = CT + n_ct;
    // aliases (lifetime-disjoint):
    unsigned short* uTt = ynT;                    // uTt dead before y5n writes ynT
    unsigned short* Wt2 = (unsigned short*)pKV;   // Wt2 dead before k_kvm writes pKV

    k_wb2<<<160, 256, 0, stream>>>(in_proj_w, Wt2);

    dim3 gt(L / 32, CIN / 32, BATCH);
    k_uT<<<gt, 256, 0, stream>>>(u, uTt);

    k_wprep<<<(COUT * DSSM) / 256, 256, 0, stream>>>(out_w, Wb2);

    dim3 g1(L / 128, 10, BATCH);
    k_inprojm<<<g1, 256, 0, stream>>>(Wt2, uTt, zx);

    k_dtdA<<<BATCH * NH * L / 256, 256, 0, stream>>>(zx, conv_dt_w, dt_bias, A_log, dAb);

    k_xbc<<<BATCH * CONVD * (L / 8) / 256, 256, 0, stream>>>(zx, conv_xBC_w, conv_xBC_b, xbc);

    dim3 gct(L / 32, DSTATE / 32, BATCH);
    k_ct<<<gct, 256, 0, stream>>>(xbc, CT);

    dim3 g4(8, NH, BATCH);
    k_kvm<<<g4, 256, 0, stream>>>(xbc, dAb, pKV);
    k_kvrt<<<BATCH * NH, 256, 0, stream>>>(pKV, KVt);

    dim3 g5(L / 32, BATCH);
    k_y5n<<<g5, 256, 0, stream>>>(CT, KVt, xbc, zx, conv_z_w, conv_z_b, D_param, norm_w, ynT);

    dim3 g6(HH / 2, COUT / 64, BATCH);
    k_conv3m<<<g6, 256, 0, stream>>>(ynT, Wb2, out);
}

// Round 15
// 238.864 us; speedup vs baseline: 1.0798x; 1.0798x over previous
//
#include <hip/hip_runtime.h>
#include <math.h>

// ---------------------------------------------------------------------------
// Mamba2-style 2D SSM block. bf16 intermediates + MFMA for inproj/KV/conv3.
// B=8, D_MODEL=256, L=64*64=4096, D_IN_PROJ=1160, D_SSM=512, NH=8, HD=64,
// D_STATE=64, CONV_DIM=640, COUT=256.
// ---------------------------------------------------------------------------

constexpr int BATCH  = 8;
constexpr int CIN    = 256;
constexpr int HH     = 64, WW = 64;
constexpr int L      = HH * WW;      // 4096
constexpr int DPROJ  = 1160;
constexpr int DSSM   = 512;
constexpr int DSTATE = 64;
constexpr int NH     = 8;
constexpr int HD     = 64;
constexpr int CONVD  = 640;
constexpr int COUT   = 256;
constexpr float EPS  = 1e-5f;

typedef __attribute__((ext_vector_type(8))) short short8;   // 8 bf16 (4 VGPR)
typedef __attribute__((ext_vector_type(4))) float f32x4;

static __device__ __forceinline__ float silu_f(float x) {
    return x / (1.f + __expf(-x));
}
static __device__ __forceinline__ float bf2f(unsigned short u) {
    return __uint_as_float(((unsigned)u) << 16);
}
static __device__ __forceinline__ unsigned short f2bf(float f) {
    unsigned x = __float_as_uint(f);
    unsigned r = (x + 0x7FFFu + ((x >> 16) & 1u)) >> 16;   // RNE
    return (unsigned short)r;
}

// async global->LDS, 16B per lane (dest must be wave-uniform base + lane*16)
static __device__ __forceinline__ void gl2lds16(const unsigned short* g, short* l) {
    __builtin_amdgcn_global_load_lds(
        (const __attribute__((address_space(1))) unsigned int*)g,
        (__attribute__((address_space(3))) unsigned int*)l, 16, 0, 0);
}

// ---------------------------------------------------------------------------
// K0 (merged prep): blockIdx ranges ->
//  [0,160):        in_proj weights -> Wt2 bf16 K-tiles, XOR-swizzled slots
//  [160,160+8192): u f32 [b][c][l] -> uTt bf16 K-tiles (same layout)
//  [8352,8864):    conv3 weights -> Wb2[tap][ci>>3][co][ci&7]
// ---------------------------------------------------------------------------
__global__ __launch_bounds__(256) void k_prep(const float* __restrict__ W,
                                              const float* __restrict__ u,
                                              const float* __restrict__ Wt,
                                              unsigned short* __restrict__ Wt2,
                                              unsigned short* __restrict__ uTt,
                                              unsigned short* __restrict__ Wb2) {
    __shared__ float Ts[32][33];
    int bx = blockIdx.x;
    int tid = threadIdx.x;

    if (bx < 160) {
        // ---- wb2: in_proj -> Wt2 tiles
        int idx8 = bx * 256 + tid;                   // 0..40959
        int tile = idx8 >> 9;                        // 0..79 = oblk*8 + ks
        int within = (idx8 & 511) * 8;
        int row = within >> 5;
        int slp = (within >> 3) & 3;
        int oblk = tile >> 3, ks = tile & 7;
        int o = oblk * 128 + row;
        int c = ks * 32 + (slp ^ (row & 3)) * 8;
        unsigned short s[8] = {0, 0, 0, 0, 0, 0, 0, 0};
        if (o < DPROJ) {
            float4 v0 = *(const float4*)(W + (size_t)o * CIN + c);
            float4 v1 = *(const float4*)(W + (size_t)o * CIN + c + 4);
            s[0] = f2bf(v0.x); s[1] = f2bf(v0.y); s[2] = f2bf(v0.z); s[3] = f2bf(v0.w);
            s[4] = f2bf(v1.x); s[5] = f2bf(v1.y); s[6] = f2bf(v1.z); s[7] = f2bf(v1.w);
        }
        *(uint4*)(Wt2 + (size_t)tile * 4096 + within) = *(uint4*)s;
    } else if (bx < 160 + 8192) {
        // ---- uT: 32x32 tile transpose+cast into uTt tiles
        int t = bx - 160;
        int l0 = (t & 127) * 32;
        int c0 = ((t >> 7) & 7) * 32;
        int b  = t >> 10;
        {
            int r = tid >> 3, c4 = tid & 7;
            float4 v = *(const float4*)(u + ((size_t)b * CIN + c0 + r) * L + l0 + c4 * 4);
            Ts[r][c4 * 4 + 0] = v.x;
            Ts[r][c4 * 4 + 1] = v.y;
            Ts[r][c4 * 4 + 2] = v.z;
            Ts[r][c4 * 4 + 3] = v.w;
        }
        __syncthreads();
        {
            int lr = tid >> 3, cg = tid & 7;
            unsigned short s[4];
#pragma unroll
            for (int j = 0; j < 4; ++j) s[j] = f2bf(Ts[cg * 4 + j][lr]);
            int lg = l0 + lr;
            int tile = ((b * 32 + (lg >> 7)) << 3) + (c0 >> 5);
            int row = lg & 127;
            int slot = (cg >> 1) ^ (row & 3);
            size_t off = (size_t)tile * 4096 + row * 32 + slot * 8 + (cg & 1) * 4;
            *(uint2*)(uTt + off) = *(uint2*)s;
        }
    } else {
        // ---- wprep: conv3 weights
        int i = (bx - (160 + 8192)) * 256 + tid;     // co*512 + ci
        int co = i >> 9, ci = i & 511;
        const float* src = Wt + (size_t)i * 9;
#pragma unroll
        for (int tap = 0; tap < 9; ++tap) {
            Wb2[(((size_t)tap * 64 + (ci >> 3)) * 256 + co) * 8 + (ci & 7)] = f2bf(src[tap]);
        }
    }
}

// ---------------------------------------------------------------------------
// K1: in-projection via MFMA, m97-style staging, double buffer, swizzled
// ds_read_b128, one barrier per K-step. 128l x 128o block, 4 waves (2x2).
// ---------------------------------------------------------------------------
__global__ __launch_bounds__(256) void k_inprojm(const unsigned short* __restrict__ Wt2,
                                                 const unsigned short* __restrict__ uTt,
                                                 unsigned short* __restrict__ zx) {
    __shared__ short Ab[2][4096];      // 8 KB each
    __shared__ short Bbuf[2][4096];
    int lblk = blockIdx.x, oblk = blockIdx.y, b = blockIdx.z;
    int tid = threadIdx.x, lane = tid & 63, w = tid >> 6;
    int laneN = lane & 15, laneK = lane >> 4;

    const unsigned short* At = uTt + (size_t)(b * 32 + lblk) * 8 * 4096;
    const unsigned short* Bt = Wt2 + (size_t)oblk * 8 * 4096;

    f32x4 acc[4][4];
#pragma unroll
    for (int mt = 0; mt < 4; ++mt)
#pragma unroll
        for (int nt = 0; nt < 4; ++nt) acc[mt][nt] = (f32x4){0.f, 0.f, 0.f, 0.f};

    gl2lds16(At + tid * 8,        &Ab[0][tid * 8]);
    gl2lds16(At + 2048 + tid * 8, &Ab[0][2048 + tid * 8]);
    gl2lds16(Bt + tid * 8,        &Bbuf[0][tid * 8]);
    gl2lds16(Bt + 2048 + tid * 8, &Bbuf[0][2048 + tid * 8]);
    __syncthreads();

    int arow = (w & 1) * 64;
    int brow = (w >> 1) * 64;
    int asl = (laneK ^ (laneN & 3)) * 8;

    int cur = 0;
    for (int ks = 0; ks < 8; ++ks) {
        if (ks < 7) {
            const unsigned short* an = At + (size_t)(ks + 1) * 4096;
            const unsigned short* bn = Bt + (size_t)(ks + 1) * 4096;
            int c2 = cur ^ 1;
            gl2lds16(an + tid * 8,        &Ab[c2][tid * 8]);
            gl2lds16(an + 2048 + tid * 8, &Ab[c2][2048 + tid * 8]);
            gl2lds16(bn + tid * 8,        &Bbuf[c2][tid * 8]);
            gl2lds16(bn + 2048 + tid * 8, &Bbuf[c2][2048 + tid * 8]);
        }
        short8 av[4], bv[4];
#pragma unroll
        for (int mt = 0; mt < 4; ++mt)
            av[mt] = *(const short8*)&Ab[cur][(arow + mt * 16 + laneN) * 32 + asl];
#pragma unroll
        for (int nt = 0; nt < 4; ++nt)
            bv[nt] = *(const short8*)&Bbuf[cur][(brow + nt * 16 + laneN) * 32 + asl];
#pragma unroll
        for (int mt = 0; mt < 4; ++mt)
#pragma unroll
            for (int nt = 0; nt < 4; ++nt)
                acc[mt][nt] = __builtin_amdgcn_mfma_f32_16x16x32_bf16(av[mt], bv[nt], acc[mt][nt], 0, 0, 0);
        __syncthreads();
        cur ^= 1;
    }

    unsigned short* zb = zx + (size_t)b * DPROJ * L;
    int lbase = lblk * 128 + arow;
#pragma unroll
    for (int nt = 0; nt < 4; ++nt) {
        int o = oblk * 128 + brow + nt * 16 + laneN;
        if (o < DPROJ) {
#pragma unroll
            for (int mt = 0; mt < 4; ++mt) {
                unsigned short s[4] = {f2bf(acc[mt][nt].x), f2bf(acc[mt][nt].y),
                                       f2bf(acc[mt][nt].z), f2bf(acc[mt][nt].w)};
                *(uint2*)(zb + (size_t)o * L + lbase + mt * 16 + laneK * 4) = *(uint2*)s;
            }
        }
    }
}

// ---------------------------------------------------------------------------
// K2 (merged): blocks [0,10240): xBC causal conv (K=3)+SiLU (vectorized x8);
//              blocks [10240,11264): dt causal conv (K=4)+SiLU -> dA.
// ---------------------------------------------------------------------------
__global__ __launch_bounds__(256) void k_conv1(const unsigned short* __restrict__ zx,
                                               const float* __restrict__ cw,
                                               const float* __restrict__ cb,
                                               const float* __restrict__ dw,
                                               const float* __restrict__ db,
                                               const float* __restrict__ Alog,
                                               unsigned short* __restrict__ xbc,
                                               float* __restrict__ dA) {
    int bx = blockIdx.x;
    int tid = threadIdx.x;
    if (bx < 10240) {
        int idx = bx * 256 + tid;
        int lg = idx & (L / 8 - 1);
        int c  = (idx >> 9) % CONVD;
        int b  = idx / (CONVD * (L / 8));
        int l0 = lg * 8;
        const unsigned short* row = zx + ((size_t)b * DPROJ + DSSM + c) * L;
        float x[10];
        uint4 raw = *(const uint4*)(row + l0);
        const unsigned short* s = (const unsigned short*)&raw;
#pragma unroll
        for (int t = 0; t < 8; ++t) x[2 + t] = bf2f(s[t]);
        if (l0 > 0) { x[0] = bf2f(row[l0 - 2]); x[1] = bf2f(row[l0 - 1]); }
        else        { x[0] = 0.f; x[1] = 0.f; }
        float w0 = cw[c * 3 + 0], w1 = cw[c * 3 + 1], w2 = cw[c * 3 + 2], bb = cb[c];
        uint4 o;
        unsigned short* os = (unsigned short*)&o;
#pragma unroll
        for (int t = 0; t < 8; ++t) {
            float y = bb + w0 * x[t] + w1 * x[t + 1] + w2 * x[t + 2];
            os[t] = f2bf(silu_f(y));
        }
        *(uint4*)(xbc + ((size_t)b * CONVD + c) * L + l0) = o;
    } else {
        int idx = (bx - 10240) * 256 + tid;   // (b*NH + h)*L + l
        int l = idx & (L - 1);
        int h = (idx >> 12) & (NH - 1);
        int b = idx >> 15;
        const unsigned short* row = zx + ((size_t)b * DPROJ + DSSM + CONVD + h) * L;
        float y = db[h];
#pragma unroll
        for (int k = 0; k < 4; ++k) {
            int ls = l + k - 3;
            if (ls >= 0) y += dw[h * 4 + k] * bf2f(row[ls]);
        }
        dA[idx] = silu_f(y) * (-__expf(Alog[h]));
    }
}

// ---------------------------------------------------------------------------
// K4: KV via MFMA. Per (b,h): KV[n][d] = sum_l (B[l][n]*dA[l]) * V[l][d].
// ---------------------------------------------------------------------------
__global__ __launch_bounds__(256) void k_kvm(const unsigned short* __restrict__ xbc,
                                             const float* __restrict__ dA,
                                             float* __restrict__ pKV) {
    __shared__ float red[4][4096];             // 64 KB
    int kc = blockIdx.x, h = blockIdx.y, b = blockIdx.z;
    int tid = threadIdx.x, lane = tid & 63, w = tid >> 6;
    int laneN = lane & 15, laneK = lane >> 4;

    const unsigned short* Bb = xbc + ((size_t)b * CONVD + DSSM) * L;
    const unsigned short* Vb = xbc + ((size_t)b * CONVD + h * HD) * L;
    const float* dAp = dA + ((size_t)b * NH + h) * L;

    f32x4 acc[4][4];
#pragma unroll
    for (int mt = 0; mt < 4; ++mt)
#pragma unroll
        for (int nt = 0; nt < 4; ++nt) acc[mt][nt] = (f32x4){0.f, 0.f, 0.f, 0.f};

    int kbase = kc * 512 + w * 128;
#pragma unroll
    for (int ks = 0; ks < 4; ++ks) {
        int kl = kbase + ks * 32 + laneK * 8;
        float4 da0 = *(const float4*)(dAp + kl);
        float4 da1 = *(const float4*)(dAp + kl + 4);
        float dav[8] = {da0.x, da0.y, da0.z, da0.w, da1.x, da1.y, da1.z, da1.w};
        short8 afr[4];
#pragma unroll
        for (int mt = 0; mt < 4; ++mt) {
            uint4 raw = *(const uint4*)(Bb + (size_t)(mt * 16 + laneN) * L + kl);
            const unsigned short* s = (const unsigned short*)&raw;
            short8 af;
#pragma unroll
            for (int j = 0; j < 8; ++j) af[j] = (short)f2bf(bf2f(s[j]) * dav[j]);
            afr[mt] = af;
        }
#pragma unroll
        for (int nt = 0; nt < 4; ++nt) {
            short8 bfr = *(const short8*)(Vb + (size_t)(nt * 16 + laneN) * L + kl);
#pragma unroll
            for (int mt = 0; mt < 4; ++mt)
                acc[mt][nt] = __builtin_amdgcn_mfma_f32_16x16x32_bf16(afr[mt], bfr, acc[mt][nt], 0, 0, 0);
        }
    }

#pragma unroll
    for (int mt = 0; mt < 4; ++mt)
#pragma unroll
        for (int nt = 0; nt < 4; ++nt)
#pragma unroll
            for (int j = 0; j < 4; ++j)
                red[w][(mt * 16 + laneK * 4 + j) * 64 + nt * 16 + laneN] = acc[mt][nt][j];
    __syncthreads();

    float* dst = pKV + (((size_t)(b * NH + h) * 8 + kc) * 4096);
#pragma unroll
    for (int q = 0; q < 4; ++q) {
        int off = q * 1024 + tid * 4;
        float4 s0 = *(const float4*)&red[0][off];
        float4 s1 = *(const float4*)&red[1][off];
        float4 s2 = *(const float4*)&red[2][off];
        float4 s3 = *(const float4*)&red[3][off];
        float4 r;
        r.x = s0.x + s1.x + s2.x + s3.x;
        r.y = s0.y + s1.y + s2.y + s3.y;
        r.z = s0.z + s1.z + s2.z + s3.z;
        r.w = s0.w + s1.w + s2.w + s3.w;
        *(float4*)(dst + off) = r;
    }
}

// K4b: reduce 8 k-chunk partials -> KV
__global__ __launch_bounds__(256) void k_kvred(const float* __restrict__ pKV,
                                               float* __restrict__ KV) {
    int flat4 = blockIdx.x * 256 + threadIdx.x;
    int bh = flat4 >> 10;
    int nd = (flat4 & 1023) * 4;
    float4 r = make_float4(0.f, 0.f, 0.f, 0.f);
#pragma unroll
    for (int kc = 0; kc < 8; ++kc) {
        float4 v = *(const float4*)(pKV + ((size_t)bh * 8 + kc) * 4096 + nd);
        r.x += v.x; r.y += v.y; r.z += v.z; r.w += v.w;
    }
    *(float4*)(KV + (size_t)bh * 4096 + nd) = r;
}

// ---------------------------------------------------------------------------
// K5a: y = C·KV + V*D, gate with silu(silu(conv_z)); yg (bf16) into zx rows
// [512..1023] per batch.
// ---------------------------------------------------------------------------
constexpr int Y_LT = 128;

__global__ __launch_bounds__(256) void k_y5a(const unsigned short* __restrict__ xbc,
                                             const unsigned short* __restrict__ zx,
                                             const float* __restrict__ KV,
                                             const float* __restrict__ zw,
                                             const float* __restrict__ zb,
                                             const float* __restrict__ Dp,
                                             unsigned short* __restrict__ ygout) {
    __shared__ float Cs[DSTATE][Y_LT + 4];
    __shared__ float KVs[DSTATE][HD + 4];
    int l0 = blockIdx.x * Y_LT;
    int h  = blockIdx.y;
    int b  = blockIdx.z;
    int tid = threadIdx.x;
    int td = tid >> 4, tl = tid & 15;

    const unsigned short* xb = xbc + (size_t)b * CONVD * L;
#pragma unroll
    for (int j = 0; j < 4; ++j) {
        int i = j * 256 + tid;
        int nn = i >> 4, c8 = i & 15;
        uint4 raw = *(const uint4*)(xb + (size_t)(DSSM + DSTATE + nn) * L + l0 + c8 * 8);
        const unsigned short* s = (const unsigned short*)&raw;
#pragma unroll
        for (int t = 0; t < 8; ++t) Cs[nn][c8 * 8 + t] = bf2f(s[t]);
    }
    const float* kvb = KV + ((size_t)b * NH + h) * DSTATE * HD;
#pragma unroll
    for (int j = 0; j < 4; ++j) {
        int i = j * 256 + tid;
        int nn = i >> 4, d4 = i & 15;
        *(float4*)&KVs[nn][d4 * 4] = *(const float4*)(kvb + (size_t)nn * HD + d4 * 4);
    }
    __syncthreads();

    float acc[4][8];
#pragma unroll
    for (int i = 0; i < 4; ++i)
#pragma unroll
        for (int j = 0; j < 8; ++j) acc[i][j] = 0.f;

    for (int nn = 0; nn < DSTATE; ++nn) {
        float4 kv = *(const float4*)&KVs[nn][td * 4];
        float cl[8];
        *(float4*)&cl[0] = *(const float4*)&Cs[nn][tl * 8];
        *(float4*)&cl[4] = *(const float4*)&Cs[nn][tl * 8 + 4];
#pragma unroll
        for (int j = 0; j < 8; ++j) {
            acc[0][j] += kv.x * cl[j];
            acc[1][j] += kv.y * cl[j];
            acc[2][j] += kv.z * cl[j];
            acc[3][j] += kv.w * cl[j];
        }
    }

    float Dh = Dp[h];
    int lbase = l0 + tl * 8;
#pragma unroll
    for (int dj = 0; dj < 4; ++dj) {
        int c = h * HD + td * 4 + dj;
        float v[8];
        {
            uint4 raw = *(const uint4*)(xb + (size_t)c * L + lbase);
            const unsigned short* s = (const unsigned short*)&raw;
#pragma unroll
            for (int t = 0; t < 8; ++t) v[t] = bf2f(s[t]);
        }
        const unsigned short* zrow = zx + ((size_t)b * DPROJ + c) * L;
        float zv[12];
        if (lbase >= 4) {
            uint2 z0 = *(const uint2*)(zrow + lbase - 4);
            const unsigned short* s = (const unsigned short*)&z0;
#pragma unroll
            for (int t = 0; t < 4; ++t) zv[t] = bf2f(s[t]);
        } else {
            zv[0] = zv[1] = zv[2] = zv[3] = 0.f;
        }
        {
            uint4 z1 = *(const uint4*)(zrow + lbase);
            const unsigned short* s = (const unsigned short*)&z1;
#pragma unroll
            for (int t = 0; t < 8; ++t) zv[4 + t] = bf2f(s[t]);
        }
        float w0 = zw[c * 3 + 0], w1 = zw[c * 3 + 1], w2 = zw[c * 3 + 2];
        float bz = zb[c];
        uint4 pk;
        unsigned short* sp = (unsigned short*)&pk;
#pragma unroll
        for (int lj = 0; lj < 8; ++lj) {
            float y = acc[dj][lj] + v[lj] * Dh;
            float zy = bz + w0 * zv[lj + 2] + w1 * zv[lj + 3] + w2 * zv[lj + 4];
            sp[lj] = f2bf(y * silu_f(silu_f(zy)));
        }
        *(uint4*)(ygout + (size_t)b * DPROJ * L + (size_t)c * L + lbase) = pk;
    }
}

// ---------------------------------------------------------------------------
// K5b: RMSNorm over 512 channels per (b,l); writes ynT[b][l][c] (NHWC, bf16).
// Global reads vectorized (uint4 = 8 bf16 per lane).
// ---------------------------------------------------------------------------
constexpr int R_LT = 32;

__global__ __launch_bounds__(256) void k_y5bT(const unsigned short* __restrict__ yg,
                                              const float* __restrict__ nw,
                                              unsigned short* __restrict__ ynT) {
    __shared__ float ygs[DSSM][R_LT + 1];
    __shared__ float red[8][R_LT];
    __shared__ float rs[R_LT];
    int l0 = blockIdx.x * R_LT;
    int b  = blockIdx.y;
    int tid = threadIdx.x;
    int ll = tid & 31, grp = tid >> 5;
    const unsigned short* ygb = yg + (size_t)b * DPROJ * L;
#pragma unroll
    for (int j = 0; j < 8; ++j) {
        int i = j * 256 + tid;          // 0..2047
        int c = i >> 2, q = i & 3;      // row c, 8-elem group q
        uint4 raw = *(const uint4*)(ygb + (size_t)c * L + l0 + q * 8);
        const unsigned short* s = (const unsigned short*)&raw;
#pragma unroll
        for (int t = 0; t < 8; ++t) ygs[c][q * 8 + t] = bf2f(s[t]);
    }
    __syncthreads();
    float ss = 0.f;
#pragma unroll
    for (int ci = 0; ci < 64; ++ci) {
        float t = ygs[grp * 64 + ci][ll];
        ss += t * t;
    }
    red[grp][ll] = ss;
    __syncthreads();
    if (tid < R_LT) {
        float s = 0.f;
#pragma unroll
        for (int g = 0; g < 8; ++g) s += red[g][tid];
        rs[tid] = rsqrtf(s * (1.f / DSSM) + EPS);
    }
    __syncthreads();
    int lc = tid & 31, cg = tid >> 5;
    float r = rs[lc];
    unsigned short* dst = ynT + ((size_t)b * L + l0 + lc) * DSSM + cg * 64;
#pragma unroll
    for (int j = 0; j < 8; ++j) {
        uint4 pk;
        unsigned short* sp = (unsigned short*)&pk;
#pragma unroll
        for (int t = 0; t < 8; ++t) {
            int c = cg * 64 + j * 8 + t;
            sp[t] = f2bf(ygs[c][lc] * r * nw[c]);
        }
        *(uint4*)(dst + j * 8) = pk;
    }
}

// ---------------------------------------------------------------------------
// K6: 3x3 conv2d SAME via bf16 MFMA implicit GEMM. Block 128px (2 rows) x
// 64co; wave 64px x 32co (acc[4][2]); ci-step 64; A in LDS (38 KB, reg-
// prefetch dbuf); B streamed from L2 one-tap-ahead. 4 blocks/CU.
// ---------------------------------------------------------------------------
__global__ __launch_bounds__(256, 4) void k_conv3m(const unsigned short* __restrict__ ynT,
                                                   const unsigned short* __restrict__ Wb2,
                                                   float* __restrict__ out) {
    __shared__ short Alds[4 * 66 * 72];        // 38016 B
    int h0  = blockIdx.x * 2;
    int co0 = blockIdx.y * 64;
    int b   = blockIdx.z;
    int tid  = threadIdx.x;
    int lane = tid & 63;
    int wid  = tid >> 6;
    int wm = wid >> 1, wn = wid & 1;
    int laneN = lane & 15, laneK = lane >> 4;

    f32x4 acc[4][2];
#pragma unroll
    for (int mt = 0; mt < 4; ++mt)
#pragma unroll
        for (int nt = 0; nt < 2; ++nt) acc[mt][nt] = (f32x4){0.f, 0.f, 0.f, 0.f};

    const unsigned short* ynb = ynT + (size_t)b * L * DSSM;

    const int a_wi1 = tid >> 2, a_sl = tid & 3;

    if (tid < 64) {
        int rw = tid >> 3, q = tid & 7;
        int r = rw >> 1, wi = (rw & 1) ? 65 : 0;
        *(uint4*)&Alds[(r * 66 + wi) * 72 + q * 8] = make_uint4(0u, 0u, 0u, 0u);
    }

    uint4 pA[8];
#pragma unroll
    for (int j = 0; j < 4; ++j) {
        int hrow = h0 - 1 + j;
        bool ok = (hrow >= 0 && hrow < HH);
        const unsigned short* src = ynb + (size_t)(hrow * WW + a_wi1) * DSSM;
#pragma unroll
        for (int s2 = 0; s2 < 2; ++s2) {
            pA[j * 2 + s2] = make_uint4(0u, 0u, 0u, 0u);
            if (ok) pA[j * 2 + s2] = *(const uint4*)(src + (a_sl + s2 * 4) * 8);
        }
    }

    const unsigned short* wbp =
        Wb2 + ((size_t)laneK * 256 + co0 + wn * 32 + laneN) * 8;

    for (int ci0 = 0; ci0 < DSSM; ci0 += 64) {
        __syncthreads();
#pragma unroll
        for (int j = 0; j < 4; ++j)
#pragma unroll
            for (int s2 = 0; s2 < 2; ++s2)
                *(uint4*)&Alds[(j * 66 + a_wi1 + 1) * 72 + (a_sl + s2 * 4) * 8] = pA[j * 2 + s2];
        __syncthreads();

        if (ci0 + 64 < DSSM) {
            int cin = ci0 + 64;
#pragma unroll
            for (int j = 0; j < 4; ++j) {
                int hrow = h0 - 1 + j;
                bool ok = (hrow >= 0 && hrow < HH);
                const unsigned short* src = ynb + (size_t)(hrow * WW + a_wi1) * DSSM + cin;
#pragma unroll
                for (int s2 = 0; s2 < 2; ++s2) {
                    pA[j * 2 + s2] = make_uint4(0u, 0u, 0u, 0u);
                    if (ok) pA[j * 2 + s2] = *(const uint4*)(src + (a_sl + s2 * 4) * 8);
                }
            }
        }

        const unsigned short* wbc = wbp + (size_t)(ci0 >> 3) * 2048;
        short8 bC[4];   // [ks][nt]
#pragma unroll
        for (int ks = 0; ks < 2; ++ks)
#pragma unroll
            for (int nt = 0; nt < 2; ++nt)
                bC[ks * 2 + nt] = *(const short8*)(wbc + (size_t)ks * 8192 + nt * 128);
#pragma unroll
        for (int tap = 0; tap < 9; ++tap) {
            short8 bN[4];
#pragma unroll
            for (int q = 0; q < 4; ++q) bN[q] = bC[q];
            if (tap < 8) {
#pragma unroll
                for (int ks = 0; ks < 2; ++ks)
#pragma unroll
                    for (int nt = 0; nt < 2; ++nt)
                        bN[ks * 2 + nt] = *(const short8*)(wbc + (size_t)(tap + 1) * 131072 +
                                                          (size_t)ks * 8192 + nt * 128);
            }
            const int kh = tap / 3, kw = tap % 3;
#pragma unroll
            for (int ks = 0; ks < 2; ++ks) {
#pragma unroll
                for (int mt = 0; mt < 4; ++mt) {
                    short8 af = *(const short8*)&Alds[((wm + kh) * 66 + laneN + mt * 16 + kw) * 72 +
                                                      (laneK + ks * 4) * 8];
                    acc[mt][0] = __builtin_amdgcn_mfma_f32_16x16x32_bf16(af, bC[ks * 2 + 0], acc[mt][0], 0, 0, 0);
                    acc[mt][1] = __builtin_amdgcn_mfma_f32_16x16x32_bf16(af, bC[ks * 2 + 1], acc[mt][1], 0, 0, 0);
                }
            }
#pragma unroll
            for (int q = 0; q < 4; ++q) bC[q] = bN[q];
        }
    }

    float* ob = out + (size_t)b * COUT * L + (size_t)(h0 + wm) * WW;
#pragma unroll
    for (int mt = 0; mt < 4; ++mt) {
#pragma unroll
        for (int nt = 0; nt < 2; ++nt) {
            int co = co0 + wn * 32 + nt * 16 + laneN;
            float4 v = make_float4(acc[mt][nt].x, acc[mt][nt].y, acc[mt][nt].z, acc[mt][nt].w);
            *(float4*)(ob + (size_t)co * L + mt * 16 + laneK * 4) = v;
        }
    }
}

// ---------------------------------------------------------------------------
extern "C" void kernel_launch(void* const* d_in, const int* in_sizes, int n_in,
                              void* d_out, int out_size, void* d_ws, size_t ws_size,
                              hipStream_t stream) {
    const float* u          = (const float*)d_in[0];
    const float* in_proj_w  = (const float*)d_in[1];
    const float* conv_dt_w  = (const float*)d_in[2];
    const float* dt_bias    = (const float*)d_in[3];
    const float* conv_xBC_w = (const float*)d_in[4];
    const float* conv_xBC_b = (const float*)d_in[5];
    const float* conv_z_w   = (const float*)d_in[6];
    const float* conv_z_b   = (const float*)d_in[7];
    const float* A_log      = (const float*)d_in[8];
    const float* D_param    = (const float*)d_in[9];
    const float* norm_w     = (const float*)d_in[10];
    const float* out_w      = (const float*)d_in[11];
    float* out = (float*)d_out;

    // ws: zx(bf16) | xbc(bf16) | ynT(bf16) | dA(f32) | KV(f32) | pKV(f32) | Wb2(bf16)
    const size_t n_zx  = (size_t)BATCH * DPROJ * L;
    const size_t n_xbc = (size_t)BATCH * CONVD * L;
    const size_t n_yn  = (size_t)BATCH * DSSM * L;
    const size_t n_dA  = (size_t)BATCH * NH * L;
    const size_t n_KV  = (size_t)BATCH * NH * DSTATE * HD;       // 262144
    const size_t n_pKV = (size_t)BATCH * NH * 8 * DSTATE * HD;   // 2097152
    const size_t n_Wb2 = (size_t)9 * 64 * 256 * 8;
    const size_t need  = 2 * (n_zx + n_xbc + n_yn + n_Wb2) + 4 * (n_dA + n_KV + n_pKV);
    if (ws_size < need) return;

    unsigned short* zx  = (unsigned short*)d_ws;
    unsigned short* xbc = zx + n_zx;
    unsigned short* ynT = xbc + n_xbc;
    float*          dAb = (float*)(ynT + n_yn);
    float*          KV  = dAb + n_dA;
    float*          pKV = KV + n_KV;
    unsigned short* Wb2 = (unsigned short*)(pKV + n_pKV);
    // aliases (lifetime-disjoint):
    unsigned short* uTt  = ynT;                    // uTt dead before y5bT writes ynT
    unsigned short* Wt2  = (unsigned short*)pKV;   // Wt2 dead before k_kvm writes pKV
    unsigned short* ygbuf = zx + (size_t)DSSM * L; // zx rows [512..1023] per batch

    // prep: wb2 (160) + uT (8192) + wprep (512) = 8864 blocks
    k_prep<<<8864, 256, 0, stream>>>(in_proj_w, u, out_w, Wt2, uTt, Wb2);

    dim3 g1(L / 128, 10, BATCH);
    k_inprojm<<<g1, 256, 0, stream>>>(Wt2, uTt, zx);

    // conv1: xbc (10240) + dtdA (1024) = 11264 blocks
    k_conv1<<<11264, 256, 0, stream>>>(zx, conv_xBC_w, conv_xBC_b,
                                       conv_dt_w, dt_bias, A_log, xbc, dAb);

    dim3 g4(8, NH, BATCH);
    k_kvm<<<g4, 256, 0, stream>>>(xbc, dAb, pKV);
    k_kvred<<<256, 256, 0, stream>>>(pKV, KV);

    dim3 g5(L / Y_LT, NH, BATCH);
    k_y5a<<<g5, 256, 0, stream>>>(xbc, zx, KV, conv_z_w, conv_z_b, D_param, ygbuf);

    dim3 g5b(L / R_LT, BATCH);
    k_y5bT<<<g5b, 256, 0, stream>>>(ygbuf, norm_w, ynT);

    dim3 g6(HH / 2, COUT / 64, BATCH);
    k_conv3m<<<g6, 256, 0, stream>>>(ynT, Wb2, out);
}